// Round 10
// baseline (370.122 us; speedup 1.0000x reference)
//
#include <hip/hip_runtime.h>
#include <hip/hip_bf16.h>

// HEALPixTransformer: B=2, Nt=768, E=512, H=8, hd=64, T=256, F=64, L=4
// Round 10: attn QBLK=32 (2-wave blocks, 384 blocks); qkv/mlp1 on 128x64 tiles
// (acc[2][4]/wave, 12 ds_read : 16 MFMA per K-step). Rest = round 9.

#define NT 768
#define EDIM 512
#define E3 1536
#define E4 2048
#define NH 8
#define TB 2

typedef unsigned short ushort_t;
typedef __attribute__((ext_vector_type(8))) short bf16x8;
typedef __attribute__((ext_vector_type(4))) float f32x4;

#define GLOAD(src, dst) __builtin_amdgcn_global_load_lds( \
    (const __attribute__((address_space(1))) unsigned int*)(src), \
    (__attribute__((address_space(3))) unsigned int*)(dst), 16, 0, 0)

__device__ inline float b2f(ushort_t u) {
    unsigned int i = ((unsigned int)u) << 16; float f;
    __builtin_memcpy(&f, &i, 4); return f;
}
__device__ inline ushort_t f2b(float f) {
    __hip_bfloat16 h = __float2bfloat16(f);
    ushort_t u; __builtin_memcpy(&u, &h, 2); return u;
}
__device__ inline float gelu_tanh(float u) {
    float z = 1.5957691216057308f * (u + 0.044715f * u * u * u);
    z = fminf(z, 40.f);
    float t = __expf(z);
    float th = (t - 1.f) / (t + 1.f);
    return 0.5f * u * (1.f + th);
}

// ---------------- bias table via MFMA (vnorm fused): biasT[b][h][q][k] ----------------
__global__ __launch_bounds__(256) void k_bias(const float* __restrict__ vm, const float* __restrict__ W_rb,
                                              const float* __restrict__ b_rb, ushort_t* __restrict__ biasT) {
    int bq = blockIdx.x; int b = bq / NT, q = bq % NT;
    __shared__ float sv[NT * 3];
    int tid = threadIdx.x, lane = tid & 63, wave = tid >> 6;
    for (int i = tid; i < NT; i += 256) {
        const float* vp = vm + ((long)b * 3072 + i * 4) * 3;
        float s0 = vp[0] + vp[3] + vp[6] + vp[9];
        float s1 = vp[1] + vp[4] + vp[7] + vp[10];
        float s2 = vp[2] + vp[5] + vp[8] + vp[11];
        float inv = rsqrtf(s0 * s0 + s1 * s1 + s2 * s2);
        sv[i * 3 + 0] = s0 * inv; sv[i * 3 + 1] = s1 * inv; sv[i * 3 + 2] = s2 * inv;
    }

    int g = lane >> 4, col = lane & 15;
    ushort_t tw[16];
    #pragma unroll
    for (int j = 0; j < 8; ++j) {
        float wsv = (col < 8) ? W_rb[(g * 8 + j) * 8 + col] : 0.f;
        float wcv = (col < 8) ? W_rb[(32 + g * 8 + j) * 8 + col] : 0.f;
        tw[j] = f2b(wsv); tw[8 + j] = f2b(wcv);
    }
    bf16x8 bsf, bcf;
    __builtin_memcpy(&bsf, tw, 16);
    __builtin_memcpy(&bcf, tw + 8, 16);
    float brh = (col < 8) ? b_rb[col] : 0.f;
    __syncthreads();

    float vq0 = sv[q * 3], vq1 = sv[q * 3 + 1], vq2 = sv[q * 3 + 2];
    float gf = (float)(8 * g);

    for (int it = 0; it < 12; ++it) {
        int tile = (it * 4 + wave) * 16;
        int p = tile + col;
        float d0 = vq0 - sv[p * 3], d1 = vq1 - sv[p * 3 + 1], d2 = vq2 - sv[p * 3 + 2];
        float dot = 1.f - 0.5f * (d0 * d0 + d1 * d1 + d2 * d2);
        dot = fminf(1.f, fmaxf(-1.f, dot));
        float theta = acosf(dot) * (2000.f / 31.f);
        float s1, c1; __sincosf(theta, &s1, &c1);
        float sg, cg; __sincosf(theta * gf, &sg, &cg);
        ushort_t fs[16];
        #pragma unroll
        for (int j = 0; j < 8; ++j) {
            fs[j] = f2b(sg); fs[8 + j] = f2b(cg);
            float ns = sg * c1 + cg * s1;
            cg = cg * c1 - sg * s1;
            sg = ns;
        }
        bf16x8 asf, acf;
        __builtin_memcpy(&asf, fs, 16);
        __builtin_memcpy(&acf, fs + 8, 16);
        f32x4 acc = {0.f, 0.f, 0.f, 0.f};
        acc = __builtin_amdgcn_mfma_f32_16x16x32_bf16(asf, bsf, acc, 0, 0, 0);
        acc = __builtin_amdgcn_mfma_f32_16x16x32_bf16(acf, bcf, acc, 0, 0, 0);
        if (col < 8) {
            ushort_t o[4];
            #pragma unroll
            for (int r = 0; r < 4; ++r) o[r] = f2b(acc[r] + brh);
            long off = (long)(b * 8 + col) * NT * NT + (long)q * NT + tile + 4 * g;
            uint2 pk;
            pk.x = (unsigned int)o[0] | ((unsigned int)o[1] << 16);
            pk.y = (unsigned int)o[2] | ((unsigned int)o[3] << 16);
            *(uint2*)(biasT + off) = pk;
        }
    }
}

// ---------------- embed + LN(lw=0) + modulate ----------------
__global__ __launch_bounds__(256) void k_embedln(const float* __restrict__ x, const float* __restrict__ W,
                                                 const float* __restrict__ be, const float* __restrict__ pe,
                                                 const float* __restrict__ ada,
                                                 float* __restrict__ xc, ushort_t* __restrict__ ln16) {
    int row = blockIdx.x; int nt = row % NT, b = row / NT;
    __shared__ float sx[16];
    __shared__ float sm[8];
    int tid = threadIdx.x, w = tid >> 6;
    if (tid < 16) sx[tid] = x[row * 16 + tid];
    __syncthreads();
    float a0 = be[tid] + pe[nt * EDIM + tid];
    float a1 = be[tid + 256] + pe[nt * EDIM + tid + 256];
    #pragma unroll
    for (int j = 0; j < 16; ++j) {
        a0 += sx[j] * W[j * EDIM + tid];
        a1 += sx[j] * W[j * EDIM + tid + 256];
    }
    xc[(long)row * EDIM + tid] = a0;
    xc[(long)row * EDIM + tid + 256] = a1;
    float s1 = a0 + a1, s2 = a0 * a0 + a1 * a1;
    for (int o = 32; o; o >>= 1) { s1 += __shfl_down(s1, o); s2 += __shfl_down(s2, o); }
    if ((tid & 63) == 0) { sm[w] = s1; sm[4 + w] = s2; }
    __syncthreads();
    s1 = sm[0] + sm[1] + sm[2] + sm[3];
    s2 = sm[4] + sm[5] + sm[6] + sm[7];
    float mu = s1 * (1.f / 512.f);
    float var = s2 * (1.f / 512.f) - mu * mu;
    float inv = rsqrtf(var + 1e-6f);
    const float* ap = ada + (long)b * E3;   // lw = 0
    float r0 = (ap[tid] + 1.f) * ((a0 - mu) * inv) + ap[512 + tid];
    float r1 = (ap[tid + 256] + 1.f) * ((a1 - mu) * inv) + ap[512 + tid + 256];
    ln16[(long)row * EDIM + tid] = f2b(r0);
    ln16[(long)row * EDIM + tid + 256] = f2b(r1);
}

// ---------------- adaLN precompute ----------------
__global__ __launch_bounds__(256) void k_adaln(const float* __restrict__ t,
    const float* __restrict__ a1W1, const float* __restrict__ a1b1, const float* __restrict__ a1W2, const float* __restrict__ a1b2,
    const float* __restrict__ a2W1, const float* __restrict__ a2b1, const float* __restrict__ a2W2, const float* __restrict__ a2b2,
    float* __restrict__ ada) {
    int blk = blockIdx.x; int b = blk & 1, lw = blk >> 1; int which = lw & 1, l = lw >> 1;
    const float* W1 = (which ? a2W1 : a1W1) + (long)l * 256 * 256;
    const float* b1 = (which ? a2b1 : a1b1) + l * 256;
    const float* W2 = (which ? a2W2 : a1W2) + (long)l * 256 * E3;
    const float* b2 = (which ? a2b2 : a1b2) + l * E3;
    __shared__ float st[256], sh[256];
    int tid = threadIdx.x;
    st[tid] = t[b * 256 + tid];
    __syncthreads();
    float a = b1[tid];
    for (int i = 0; i < 256; ++i) a += st[i] * W1[i * 256 + tid];
    sh[tid] = a / (1.f + __expf(-a));
    __syncthreads();
    int c = blockIdx.y * 256 + tid;
    float m = b2[c];
    for (int i = 0; i < 256; ++i) m += sh[i] * W2[i * E3 + c];
    ada[(long)(lw * 2 + b) * E3 + c] = m;
}

// ---------------- all weight transposes in one dispatch ----------------
__global__ __launch_bounds__(256) void k_wTall(
        const float* __restrict__ qkvW, const float* __restrict__ outW,
        const float* __restrict__ m1W, const float* __restrict__ m2W,
        ushort_t* __restrict__ qkvWt, ushort_t* __restrict__ outWt,
        ushort_t* __restrict__ m1Wt, ushort_t* __restrict__ m2Wt) {
    int idx = blockIdx.x, l = blockIdx.y;
    const float* W; ushort_t* Wt; int Kd, Nd, ntile, ktile;
    if (idx < 192)      { W = qkvW; Wt = qkvWt; Kd = 512;  Nd = 1536; ntile = idx % 24; ktile = idx / 24; }
    else if (idx < 256) { W = outW; Wt = outWt; Kd = 512;  Nd = 512;  idx -= 192; ntile = idx % 8;  ktile = idx / 8; }
    else if (idx < 512) { W = m1W;  Wt = m1Wt;  Kd = 512;  Nd = 2048; idx -= 256; ntile = idx % 32; ktile = idx / 32; }
    else                { W = m2W;  Wt = m2Wt;  Kd = 2048; Nd = 512;  idx -= 512; ntile = idx % 8;  ktile = idx / 8; }
    const float* Wp = W + (long)l * Kd * Nd;
    ushort_t* Wtp = Wt + (long)l * Kd * Nd;
    int n0 = ntile * 64, k0 = ktile * 64;
    __shared__ float s[64][65];
    int tid = threadIdx.x;
    #pragma unroll
    for (int it = 0; it < 4; ++it) {
        int i2 = tid + it * 256;
        int r = i2 >> 4, c4 = (i2 & 15) * 4;
        float4 vv = *(const float4*)(Wp + (long)(k0 + r) * Nd + n0 + c4);
        s[r][c4] = vv.x; s[r][c4 + 1] = vv.y; s[r][c4 + 2] = vv.z; s[r][c4 + 3] = vv.w;
    }
    __syncthreads();
    #pragma unroll
    for (int it = 0; it < 4; ++it) {
        int i2 = tid + it * 256;
        int rn = i2 >> 4, ck = (i2 & 15) * 4;
        long base = (long)(n0 + rn) * Kd + k0 + ck;
        #pragma unroll
        for (int j = 0; j < 4; ++j) Wtp[base + j] = f2b(s[ck + j][rn]);
    }
}

// ---------------- fused flash attention: QBLK=32, 2 waves, dbuf, setprio ----------------
__global__ __launch_bounds__(128) void k_attn(const ushort_t* __restrict__ qkv16,
        const ushort_t* __restrict__ vT, const ushort_t* __restrict__ biasT,
        ushort_t* __restrict__ attnb) {
    int qt = blockIdx.x, bh = blockIdx.y;
    int b = bh >> 3, h = bh & 7;
    __shared__ __align__(16) ushort_t Ks[2][4096];
    __shared__ __align__(16) ushort_t Vs[2][4096];
    __shared__ __align__(16) ushort_t Bi[2][2048];
    int tid = threadIdx.x, lane = tid & 63, wave = tid >> 6;   // wave in {0,1}
    int g = lane >> 4, c = lane & 15;
    int ls = lane & 7, lr = lane >> 3;
    int stg_col = (ls ^ lr) * 8;
    int q0 = qt * 32;

    bf16x8 aq[2];
    {
        const ushort_t* qp = qkv16 + ((long)(b * NT + q0 + wave * 16 + c) * E3) + h * 192;
        aq[0] = *(const bf16x8*)(qp + g * 8);
        aq[1] = *(const bf16x8*)(qp + 32 + g * 8);
    }
    float m_r[4], l_r[4];
    f32x4 o_acc[4];
    #pragma unroll
    for (int rr = 0; rr < 4; ++rr) { m_r[rr] = -1e30f; l_r[rr] = 0.f; }
    #pragma unroll
    for (int nf = 0; nf < 4; ++nf) o_acc[nf] = f32x4{0.f, 0.f, 0.f, 0.f};

#define STAGEA(buf, kt) { \
        int k0_ = (kt) * 64; \
        _Pragma("unroll") \
        for (int c0 = 0; c0 < 4; ++c0) { \
            int ch = wave * 4 + c0; \
            int row = ch * 8 + lr; \
            GLOAD(qkv16 + (long)(b * NT + k0_ + row) * E3 + h * 192 + 64 + stg_col, &Ks[buf][ch * 512]); \
            GLOAD(vT + ((long)bh * 64 + row) * NT + k0_ + stg_col, &Vs[buf][ch * 512]); \
        } \
        _Pragma("unroll") \
        for (int c0 = 0; c0 < 2; ++c0) { \
            int ch = wave * 2 + c0; \
            GLOAD(biasT + (long)bh * NT * NT + (long)(q0 + ch * 8 + lr) * NT + k0_ + ls * 8, &Bi[buf][ch * 512]); \
        } }

    STAGEA(0, 0);
    __syncthreads();
    int cur = 0;
    for (int kt = 0; kt < 12; ++kt) {
        if (kt + 1 < 12) STAGEA(cur ^ 1, kt + 1);
        f32x4 s[4];
        __builtin_amdgcn_s_setprio(1);
        #pragma unroll
        for (int nf = 0; nf < 4; ++nf) {
            s[nf] = f32x4{0.f, 0.f, 0.f, 0.f};
            #pragma unroll
            for (int kh = 0; kh < 2; ++kh) {
                int row = nf * 16 + c;
                bf16x8 bk = *(const bf16x8*)(&Ks[cur][row * 64 + (((kh * 4 + g) ^ (row & 7))) * 8]);
                s[nf] = __builtin_amdgcn_mfma_f32_16x16x32_bf16(aq[kh], bk, s[nf], 0, 0, 0);
            }
        }
        __builtin_amdgcn_s_setprio(0);
        float p[4][4], mt[4];
        #pragma unroll
        for (int rr = 0; rr < 4; ++rr) {
            int ql = wave * 16 + g * 4 + rr;
            #pragma unroll
            for (int nf = 0; nf < 4; ++nf)
                p[nf][rr] = s[nf][rr] * 0.125f + b2f(Bi[cur][ql * 64 + nf * 16 + c]);
            float mx = fmaxf(fmaxf(p[0][rr], p[1][rr]), fmaxf(p[2][rr], p[3][rr]));
            mx = fmaxf(mx, __shfl_xor(mx, 1));
            mx = fmaxf(mx, __shfl_xor(mx, 2));
            mx = fmaxf(mx, __shfl_xor(mx, 4));
            mx = fmaxf(mx, __shfl_xor(mx, 8));
            mt[rr] = mx;
        }
        #pragma unroll
        for (int rr = 0; rr < 4; ++rr) {
            float mnew = fmaxf(m_r[rr], mt[rr]);
            float sc = __expf(m_r[rr] - mnew);
            m_r[rr] = mnew;
            float rsum = 0.f;
            #pragma unroll
            for (int nf = 0; nf < 4; ++nf) {
                p[nf][rr] = __expf(p[nf][rr] - mnew);
                rsum += p[nf][rr];
            }
            rsum += __shfl_xor(rsum, 1); rsum += __shfl_xor(rsum, 2);
            rsum += __shfl_xor(rsum, 4); rsum += __shfl_xor(rsum, 8);
            l_r[rr] = l_r[rr] * sc + rsum;
            #pragma unroll
            for (int nf = 0; nf < 4; ++nf) o_acc[nf][rr] *= sc;
        }
        // P -> LDS (overlay bias slab of current buffer, wave-private rows)
        #pragma unroll
        for (int nf = 0; nf < 4; ++nf) {
            int kl = nf * 16 + c;
            int slot = kl >> 3, win = kl & 7;
            #pragma unroll
            for (int rr = 0; rr < 4; ++rr) {
                int ql = wave * 16 + g * 4 + rr;
                Bi[cur][ql * 64 + ((slot ^ (ql & 7)) * 8) + win] = f2b(p[nf][rr]);
            }
        }
        asm volatile("s_waitcnt lgkmcnt(0)" ::: "memory");
        bf16x8 ap[2];
        #pragma unroll
        for (int kh = 0; kh < 2; ++kh) {
            int ql = wave * 16 + c;
            ap[kh] = *(const bf16x8*)(&Bi[cur][ql * 64 + (((kh * 4 + g) ^ (ql & 7))) * 8]);
        }
        __builtin_amdgcn_s_setprio(1);
        #pragma unroll
        for (int nf = 0; nf < 4; ++nf) {
            #pragma unroll
            for (int kh = 0; kh < 2; ++kh) {
                int row = nf * 16 + c;
                bf16x8 bv = *(const bf16x8*)(&Vs[cur][row * 64 + (((kh * 4 + g) ^ (row & 7))) * 8]);
                o_acc[nf] = __builtin_amdgcn_mfma_f32_16x16x32_bf16(ap[kh], bv, o_acc[nf], 0, 0, 0);
            }
        }
        __builtin_amdgcn_s_setprio(0);
        __syncthreads();
        cur ^= 1;
    }
#undef STAGEA
    // normalize + transpose via Ks[0] (wave-private rows) + coalesced store
    #pragma unroll
    for (int nf = 0; nf < 4; ++nf) {
        #pragma unroll
        for (int rr = 0; rr < 4; ++rr) {
            int ql = wave * 16 + g * 4 + rr;
            Ks[0][ql * 64 + nf * 16 + c] = f2b(o_acc[nf][rr] / l_r[rr]);
        }
    }
    asm volatile("s_waitcnt lgkmcnt(0)" ::: "memory");
    __syncthreads();
    int orow = wave * 16 + (lane >> 2);
    int ocol = (lane & 3) * 16;
    const ushort_t* srcO = &Ks[0][orow * 64 + ocol];
    ushort_t* dstO = attnb + (long)(b * NT + q0 + orow) * EDIM + h * 64 + ocol;
    *(bf16x8*)(dstO) = *(const bf16x8*)(srcO);
    *(bf16x8*)(dstO + 8) = *(const bf16x8*)(srcO + 8);
}

// ---------------- MFMA GEMM, 128x64 tile (K=512), dbuf; EPI 0/1 ----------------
// 4 waves, each 32M x 64N (acc[2][4]); 12 ds_read : 16 MFMA per K-step.
template<int EPI>
__global__ __launch_bounds__(256) void k_mmA(
        const ushort_t* __restrict__ A0, const ushort_t* __restrict__ B0,
        const float* __restrict__ bias, ushort_t* __restrict__ C,
        int lda, int ldb, int ldc, ushort_t* __restrict__ vTout) {
    __shared__ __align__(16) ushort_t As[2][8192];
    __shared__ __align__(16) ushort_t Bs[2][4096];
    int tid = threadIdx.x, lane = tid & 63, wave = tid >> 6;
    int m0 = blockIdx.y * 128, n0 = blockIdx.x * 64;
    int lr = lane >> 3, ls = lane & 7;
    int stg_col = (ls ^ lr) * 8;
    int r = lane & 15, g = lane >> 4, rs = r & 7;

    f32x4 acc[2][4];
    #pragma unroll
    for (int i = 0; i < 2; ++i)
        #pragma unroll
        for (int j = 0; j < 4; ++j) acc[i][j] = f32x4{0.f, 0.f, 0.f, 0.f};

#define STAGEM(buf, t) { \
        int k0_ = (t) * 64; \
        _Pragma("unroll") \
        for (int c0 = 0; c0 < 6; ++c0) { \
            int ch = wave * 6 + c0; \
            if (ch < 16) { \
                GLOAD(A0 + (long)(m0 + ch * 8 + lr) * lda + k0_ + stg_col, &As[buf][ch * 512]); \
            } else { \
                GLOAD(B0 + (long)(n0 + (ch - 16) * 8 + lr) * ldb + k0_ + stg_col, &Bs[buf][(ch - 16) * 512]); \
            } \
        } }

    STAGEM(0, 0);
    __syncthreads();
    int cur = 0;
    for (int t = 0; t < 8; ++t) {
        if (t + 1 < 8) STAGEM(cur ^ 1, t + 1);
        bf16x8 af[2][2], bfr[4][2];
        #pragma unroll
        for (int i = 0; i < 2; ++i) {
            int row = wave * 32 + i * 16 + r;
            #pragma unroll
            for (int kh = 0; kh < 2; ++kh)
                af[i][kh] = *(const bf16x8*)(&As[cur][row * 64 + (((kh * 4 + g) ^ rs)) * 8]);
        }
        #pragma unroll
        for (int j = 0; j < 4; ++j) {
            int row = j * 16 + r;
            #pragma unroll
            for (int kh = 0; kh < 2; ++kh)
                bfr[j][kh] = *(const bf16x8*)(&Bs[cur][row * 64 + (((kh * 4 + g) ^ rs)) * 8]);
        }
        #pragma unroll
        for (int kh = 0; kh < 2; ++kh)
            #pragma unroll
            for (int i = 0; i < 2; ++i)
                #pragma unroll
                for (int j = 0; j < 4; ++j)
                    acc[i][j] = __builtin_amdgcn_mfma_f32_16x16x32_bf16(af[i][kh], bfr[j][kh], acc[i][j], 0, 0, 0);
        __syncthreads();
        cur ^= 1;
    }
#undef STAGEM

    int gr4 = g * 4, cL = lane & 15;
    #pragma unroll
    for (int i = 0; i < 2; ++i) {
        int mrow = m0 + wave * 32 + i * 16 + gr4;
        #pragma unroll
        for (int j = 0; j < 4; ++j) {
            int n = n0 + j * 16 + cL;
            float bn = bias[n];
            ushort_t o[4];
            #pragma unroll
            for (int rr = 0; rr < 4; ++rr) {
                float vv = acc[i][j][rr] + bn;
                if constexpr (EPI == 1) vv = gelu_tanh(vv);
                o[rr] = f2b(vv);
                C[(long)(mrow + rr) * ldc + n] = o[rr];
            }
            if constexpr (EPI == 0) {
                if (vTout) {
                    int seg = n % 192;
                    if (seg >= 128) {
                        int h = n / 192, d = seg - 128;
                        int b2 = (mrow >= NT) ? 1 : 0;
                        int tok = mrow - b2 * NT;
                        uint2 pk;
                        pk.x = (unsigned int)o[0] | ((unsigned int)o[1] << 16);
                        pk.y = (unsigned int)o[2] | ((unsigned int)o[3] << 16);
                        *(uint2*)(vTout + ((long)((b2 * 8 + h) * 64 + d)) * NT + tok) = pk;
                    }
                }
            }
        }
    }
}

// ---------------- MFMA GEMM, 64x64 tile, dbuf; EPI 4: fp32 split-K partial ----------------
__global__ __launch_bounds__(256) void k_mm64p(
        const ushort_t* __restrict__ A0, const ushort_t* __restrict__ B0,
        float* __restrict__ C0, int Kchunk, int lda, int ldb, int ldc) {
    __shared__ __align__(16) ushort_t As[2][4096];
    __shared__ __align__(16) ushort_t Bs[2][4096];
    int tid = threadIdx.x, lane = tid & 63, wave = tid >> 6;
    int wm = wave >> 1, wn = wave & 1;
    int m0 = blockIdx.y * 64, n0 = blockIdx.x * 64;
    int lr = lane >> 3, ls = lane & 7;
    int stg_col = (ls ^ lr) * 8;
    int r = lane & 15, g = lane >> 4, rs = r & 7;
    int nt = Kchunk >> 6;
    const ushort_t* A = A0 + (long)blockIdx.z * Kchunk;
    const ushort_t* B = B0 + (long)blockIdx.z * Kchunk;

    f32x4 acc[2][2];
    #pragma unroll
    for (int i = 0; i < 2; ++i)
        #pragma unroll
        for (int j = 0; j < 2; ++j) acc[i][j] = f32x4{0.f, 0.f, 0.f, 0.f};

#define STAGE64(buf, t) { \
        int k0_ = (t) * 64; \
        _Pragma("unroll") \
        for (int c0 = 0; c0 < 4; ++c0) { \
            int ch = wave * 4 + c0; \
            if (ch < 8) { \
                GLOAD(A + (long)(m0 + ch * 8 + lr) * lda + k0_ + stg_col, &As[buf][ch * 512]); \
            } else { \
                GLOAD(B + (long)(n0 + (ch - 8) * 8 + lr) * ldb + k0_ + stg_col, &Bs[buf][(ch - 8) * 512]); \
            } \
        } }

    STAGE64(0, 0);
    __syncthreads();
    int cur = 0;
    for (int t = 0; t < nt; ++t) {
        if (t + 1 < nt) STAGE64(cur ^ 1, t + 1);
        bf16x8 af[2][2], bfr[2][2];
        #pragma unroll
        for (int i = 0; i < 2; ++i) {
            int row = wm * 32 + i * 16 + r;
            #pragma unroll
            for (int kh = 0; kh < 2; ++kh)
                af[i][kh] = *(const bf16x8*)(&As[cur][row * 64 + (((kh * 4 + g) ^ rs)) * 8]);
        }
        #pragma unroll
        for (int j = 0; j < 2; ++j) {
            int row = wn * 32 + j * 16 + r;
            #pragma unroll
            for (int kh = 0; kh < 2; ++kh)
                bfr[j][kh] = *(const bf16x8*)(&Bs[cur][row * 64 + (((kh * 4 + g) ^ rs)) * 8]);
        }
        #pragma unroll
        for (int kh = 0; kh < 2; ++kh)
            #pragma unroll
            for (int i = 0; i < 2; ++i)
                #pragma unroll
                for (int j = 0; j < 2; ++j)
                    acc[i][j] = __builtin_amdgcn_mfma_f32_16x16x32_bf16(af[i][kh], bfr[j][kh], acc[i][j], 0, 0, 0);
        __syncthreads();
        cur ^= 1;
    }
#undef STAGE64

    int gr4 = g * 4, cL = lane & 15;
    float* C = C0 + (long)blockIdx.z * (1536 * 512);
    #pragma unroll
    for (int i = 0; i < 2; ++i) {
        int mrow = m0 + wm * 32 + i * 16 + gr4;
        #pragma unroll
        for (int j = 0; j < 2; ++j) {
            int n = n0 + wn * 32 + j * 16 + cL;
            #pragma unroll
            for (int rr = 0; rr < 4; ++rr)
                C[(long)(mrow + rr) * ldc + n] = acc[i][j][rr];
        }
    }
}

// ---------------- split-K reduce + bias + scaled residual + next LN/modulate ----------------
__global__ __launch_bounds__(256) void k_redln(const float* __restrict__ P, int kSplit,
        const float* __restrict__ bias, const float* __restrict__ ada,
        int lw_res, int lw_next,
        const float* __restrict__ xin, float* __restrict__ xout,
        ushort_t* __restrict__ lnout) {
    int tid = threadIdx.x;
    int row = blockIdx.x * 2 + (tid >> 7);
    int col = (tid & 127) * 4;
    int b = (row >= NT) ? 1 : 0;
    long idx = (long)row * EDIM + col;
    float4 s = *(const float4*)(P + idx);
    for (int kc = 1; kc < kSplit; ++kc) {
        float4 p = *(const float4*)(P + (long)kc * (1536 * 512) + idx);
        s.x += p.x; s.y += p.y; s.z += p.z; s.w += p.w;
    }
    float4 bv = *(const float4*)(bias + col);
    const float* al = ada + (long)(lw_res * 2 + b) * E3 + 1024;
    float4 av = *(const float4*)(al + col);
    float4 xv = *(const float4*)(xin + idx);
    float4 r;
    r.x = xv.x + av.x * rsqrtf(1.f + av.x * av.x) * (s.x + bv.x);
    r.y = xv.y + av.y * rsqrtf(1.f + av.y * av.y) * (s.y + bv.y);
    r.z = xv.z + av.z * rsqrtf(1.f + av.z * av.z) * (s.z + bv.z);
    r.w = xv.w + av.w * rsqrtf(1.f + av.w * av.w) * (s.w + bv.w);
    *(float4*)(xout + idx) = r;

    if (lnout) {
        float s1 = r.x + r.y + r.z + r.w;
        float s2 = r.x * r.x + r.y * r.y + r.z * r.z + r.w * r.w;
        for (int o = 32; o; o >>= 1) { s1 += __shfl_xor(s1, o); s2 += __shfl_xor(s2, o); }
        __shared__ float sm[8];
        int w = tid >> 6;
        if ((tid & 63) == 0) { sm[w] = s1; sm[4 + w] = s2; }
        __syncthreads();
        int p2 = (tid >> 7) * 2;
        s1 = sm[p2] + sm[p2 + 1];
        s2 = sm[4 + p2] + sm[4 + p2 + 1];
        float mu = s1 * (1.f / 512.f);
        float var = s2 * (1.f / 512.f) - mu * mu;
        float inv = rsqrtf(var + 1e-6f);
        const float* ap = ada + (long)(lw_next * 2 + b) * E3;
        float4 gv = *(const float4*)(ap + col);
        float4 bev = *(const float4*)(ap + 512 + col);
        ushort_t o4[4];
        o4[0] = f2b((gv.x + 1.f) * ((r.x - mu) * inv) + bev.x);
        o4[1] = f2b((gv.y + 1.f) * ((r.y - mu) * inv) + bev.y);
        o4[2] = f2b((gv.z + 1.f) * ((r.z - mu) * inv) + bev.z);
        o4[3] = f2b((gv.w + 1.f) * ((r.w - mu) * inv) + bev.w);
        uint2 pk;
        pk.x = (unsigned int)o4[0] | ((unsigned int)o4[1] << 16);
        pk.y = (unsigned int)o4[2] | ((unsigned int)o4[3] << 16);
        *(uint2*)(lnout + idx) = pk;
    }
}

extern "C" void kernel_launch(void* const* d_in, const int* in_sizes, int n_in,
                              void* d_out, int out_size, void* d_ws, size_t ws_size,
                              hipStream_t stream) {
    const float* x       = (const float*)d_in[0];
    const float* t       = (const float*)d_in[1];
    const float* vec_map = (const float*)d_in[2];
    const float* W_rb    = (const float*)d_in[3];
    const float* b_rb    = (const float*)d_in[4];
    const float* W_embed = (const float*)d_in[5];
    const float* b_embed = (const float*)d_in[6];
    const float* pos_emb = (const float*)d_in[7];
    const float* a1W1    = (const float*)d_in[8];
    const float* a1b1    = (const float*)d_in[9];
    const float* a1W2    = (const float*)d_in[10];
    const float* a1b2    = (const float*)d_in[11];
    const float* qkv_W   = (const float*)d_in[12];
    const float* qkv_b   = (const float*)d_in[13];
    const float* out_W   = (const float*)d_in[14];
    const float* out_b   = (const float*)d_in[15];
    const float* a2W1    = (const float*)d_in[16];
    const float* a2b1    = (const float*)d_in[17];
    const float* a2W2    = (const float*)d_in[18];
    const float* a2b2    = (const float*)d_in[19];
    const float* mlp_W1  = (const float*)d_in[20];
    const float* mlp_b1  = (const float*)d_in[21];
    const float* mlp_W2  = (const float*)d_in[22];
    const float* mlp_b2  = (const float*)d_in[23];

    float* ws = (float*)d_ws;
    size_t o = 0;
    ushort_t* biasT = (ushort_t*)(ws + o); o += 4718592;   // 16*768*768 bf16
    float* ada      = ws + o; o += 24576;
    float* xc       = ws + o; o += 786432;
    ushort_t* ln16  = (ushort_t*)(ws + o); o += 393216;    // 1536x512
    ushort_t* qkv16 = (ushort_t*)(ws + o); o += 1179648;   // 1536x1536
    ushort_t* vT    = (ushort_t*)(ws + o); o += 393216;    // 16x64x768
    ushort_t* attnb = (ushort_t*)(ws + o); o += 393216;    // 1536x512
    ushort_t* mlph  = (ushort_t*)(ws + o); o += 1572864;   // 1536x2048
    ushort_t* qkvWt = (ushort_t*)(ws + o); o += 1572864;   // 4x1536x512
    ushort_t* outWt = (ushort_t*)(ws + o); o += 524288;    // 4x512x512
    ushort_t* mlp1Wt = (ushort_t*)(ws + o); o += 2097152;  // 4x2048x512
    ushort_t* mlp2Wt = (ushort_t*)(ws + o); o += 2097152;  // 4x512x2048
    float* P        = ws + o; o += 3145728;                // 4 x 1536x512 f32

    k_adaln<<<dim3(16, 6), 256, 0, stream>>>(t, a1W1, a1b1, a1W2, a1b2, a2W1, a2b1, a2W2, a2b2, ada);
    k_bias<<<TB * NT, 256, 0, stream>>>(vec_map, W_rb, b_rb, biasT);
    k_embedln<<<TB * NT, 256, 0, stream>>>(x, W_embed, b_embed, pos_emb, ada, xc, ln16);
    k_wTall<<<dim3(768, 4), 256, 0, stream>>>(qkv_W, out_W, mlp_W1, mlp_W2,
                                              qkvWt, outWt, mlp1Wt, mlp2Wt);

    for (int l = 0; l < 4; ++l) {
        int lw0 = l * 2, lw1 = l * 2 + 1;
        // --- attention half (ln16 holds modulated LN for lw0) ---
        k_mmA<0><<<dim3(24, 12), 256, 0, stream>>>(
            ln16, qkvWt + (long)l * 786432, qkv_b + l * E3,
            qkv16, 512, 512, E3, vT);
        k_attn<<<dim3(24, 16), 128, 0, stream>>>(qkv16, vT, biasT, attnb);
        k_mm64p<<<dim3(8, 24, 2), 256, 0, stream>>>(
            attnb, outWt + (long)l * 262144, P, 256, 512, 512, EDIM);
        k_redln<<<768, 256, 0, stream>>>(P, 2, out_b + l * EDIM, ada, lw0, lw1, xc, xc, ln16);
        // --- mlp half (ln16 now holds lw1) ---
        k_mmA<1><<<dim3(32, 12), 256, 0, stream>>>(
            ln16, mlp1Wt + (long)l * 1048576, mlp_b1 + l * E4,
            mlph, 512, 512, E4, nullptr);
        k_mm64p<<<dim3(8, 24, 4), 256, 0, stream>>>(
            mlph, mlp2Wt + (long)l * 1048576, P, 512, 2048, 2048, EDIM);
        k_redln<<<768, 256, 0, stream>>>(P, 4, mlp_b2 + l * EDIM, ada, lw1, lw1 + 1,
            xc, (l == 3) ? (float*)d_out : xc, (l == 3) ? nullptr : ln16);
    }
}

// Round 11
// 344.509 us; speedup vs baseline: 1.0743x; 1.0743x over previous
//
#include <hip/hip_runtime.h>
#include <hip/hip_bf16.h>

// HEALPixTransformer: B=2, Nt=768, E=512, H=8, hd=64, T=256, F=64, L=4
// Round 11: exact round-9 structure (best, 347us) + XCD-aware block swizzle in
// k_attn (all 12 q-tiles of one (b,h) pinned to one XCD slot -> K/V L2 reuse).
// Round-10's bundled attn QBLK=32 + 128x64 GEMM retile reverted (regressed).

#define NT 768
#define EDIM 512
#define E3 1536
#define E4 2048
#define NH 8
#define TB 2

typedef unsigned short ushort_t;
typedef __attribute__((ext_vector_type(8))) short bf16x8;
typedef __attribute__((ext_vector_type(4))) float f32x4;

#define GLOAD(src, dst) __builtin_amdgcn_global_load_lds( \
    (const __attribute__((address_space(1))) unsigned int*)(src), \
    (__attribute__((address_space(3))) unsigned int*)(dst), 16, 0, 0)

__device__ inline float b2f(ushort_t u) {
    unsigned int i = ((unsigned int)u) << 16; float f;
    __builtin_memcpy(&f, &i, 4); return f;
}
__device__ inline ushort_t f2b(float f) {
    __hip_bfloat16 h = __float2bfloat16(f);
    ushort_t u; __builtin_memcpy(&u, &h, 2); return u;
}
__device__ inline float gelu_tanh(float u) {
    float z = 1.5957691216057308f * (u + 0.044715f * u * u * u);
    z = fminf(z, 40.f);
    float t = __expf(z);
    float th = (t - 1.f) / (t + 1.f);
    return 0.5f * u * (1.f + th);
}

// ---------------- bias table via MFMA (vnorm fused): biasT[b][h][q][k] ----------------
__global__ __launch_bounds__(256) void k_bias(const float* __restrict__ vm, const float* __restrict__ W_rb,
                                              const float* __restrict__ b_rb, ushort_t* __restrict__ biasT) {
    int bq = blockIdx.x; int b = bq / NT, q = bq % NT;
    __shared__ float sv[NT * 3];
    int tid = threadIdx.x, lane = tid & 63, wave = tid >> 6;
    for (int i = tid; i < NT; i += 256) {
        const float* vp = vm + ((long)b * 3072 + i * 4) * 3;
        float s0 = vp[0] + vp[3] + vp[6] + vp[9];
        float s1 = vp[1] + vp[4] + vp[7] + vp[10];
        float s2 = vp[2] + vp[5] + vp[8] + vp[11];
        float inv = rsqrtf(s0 * s0 + s1 * s1 + s2 * s2);
        sv[i * 3 + 0] = s0 * inv; sv[i * 3 + 1] = s1 * inv; sv[i * 3 + 2] = s2 * inv;
    }

    int g = lane >> 4, col = lane & 15;
    ushort_t tw[16];
    #pragma unroll
    for (int j = 0; j < 8; ++j) {
        float wsv = (col < 8) ? W_rb[(g * 8 + j) * 8 + col] : 0.f;
        float wcv = (col < 8) ? W_rb[(32 + g * 8 + j) * 8 + col] : 0.f;
        tw[j] = f2b(wsv); tw[8 + j] = f2b(wcv);
    }
    bf16x8 bsf, bcf;
    __builtin_memcpy(&bsf, tw, 16);
    __builtin_memcpy(&bcf, tw + 8, 16);
    float brh = (col < 8) ? b_rb[col] : 0.f;
    __syncthreads();

    float vq0 = sv[q * 3], vq1 = sv[q * 3 + 1], vq2 = sv[q * 3 + 2];
    float gf = (float)(8 * g);

    for (int it = 0; it < 12; ++it) {
        int tile = (it * 4 + wave) * 16;
        int p = tile + col;
        float d0 = vq0 - sv[p * 3], d1 = vq1 - sv[p * 3 + 1], d2 = vq2 - sv[p * 3 + 2];
        float dot = 1.f - 0.5f * (d0 * d0 + d1 * d1 + d2 * d2);
        dot = fminf(1.f, fmaxf(-1.f, dot));
        float theta = acosf(dot) * (2000.f / 31.f);
        float s1, c1; __sincosf(theta, &s1, &c1);
        float sg, cg; __sincosf(theta * gf, &sg, &cg);
        ushort_t fs[16];
        #pragma unroll
        for (int j = 0; j < 8; ++j) {
            fs[j] = f2b(sg); fs[8 + j] = f2b(cg);
            float ns = sg * c1 + cg * s1;
            cg = cg * c1 - sg * s1;
            sg = ns;
        }
        bf16x8 asf, acf;
        __builtin_memcpy(&asf, fs, 16);
        __builtin_memcpy(&acf, fs + 8, 16);
        f32x4 acc = {0.f, 0.f, 0.f, 0.f};
        acc = __builtin_amdgcn_mfma_f32_16x16x32_bf16(asf, bsf, acc, 0, 0, 0);
        acc = __builtin_amdgcn_mfma_f32_16x16x32_bf16(acf, bcf, acc, 0, 0, 0);
        if (col < 8) {
            ushort_t o[4];
            #pragma unroll
            for (int r = 0; r < 4; ++r) o[r] = f2b(acc[r] + brh);
            long off = (long)(b * 8 + col) * NT * NT + (long)q * NT + tile + 4 * g;
            uint2 pk;
            pk.x = (unsigned int)o[0] | ((unsigned int)o[1] << 16);
            pk.y = (unsigned int)o[2] | ((unsigned int)o[3] << 16);
            *(uint2*)(biasT + off) = pk;
        }
    }
}

// ---------------- embed + LN(lw=0) + modulate ----------------
__global__ __launch_bounds__(256) void k_embedln(const float* __restrict__ x, const float* __restrict__ W,
                                                 const float* __restrict__ be, const float* __restrict__ pe,
                                                 const float* __restrict__ ada,
                                                 float* __restrict__ xc, ushort_t* __restrict__ ln16) {
    int row = blockIdx.x; int nt = row % NT, b = row / NT;
    __shared__ float sx[16];
    __shared__ float sm[8];
    int tid = threadIdx.x, w = tid >> 6;
    if (tid < 16) sx[tid] = x[row * 16 + tid];
    __syncthreads();
    float a0 = be[tid] + pe[nt * EDIM + tid];
    float a1 = be[tid + 256] + pe[nt * EDIM + tid + 256];
    #pragma unroll
    for (int j = 0; j < 16; ++j) {
        a0 += sx[j] * W[j * EDIM + tid];
        a1 += sx[j] * W[j * EDIM + tid + 256];
    }
    xc[(long)row * EDIM + tid] = a0;
    xc[(long)row * EDIM + tid + 256] = a1;
    float s1 = a0 + a1, s2 = a0 * a0 + a1 * a1;
    for (int o = 32; o; o >>= 1) { s1 += __shfl_down(s1, o); s2 += __shfl_down(s2, o); }
    if ((tid & 63) == 0) { sm[w] = s1; sm[4 + w] = s2; }
    __syncthreads();
    s1 = sm[0] + sm[1] + sm[2] + sm[3];
    s2 = sm[4] + sm[5] + sm[6] + sm[7];
    float mu = s1 * (1.f / 512.f);
    float var = s2 * (1.f / 512.f) - mu * mu;
    float inv = rsqrtf(var + 1e-6f);
    const float* ap = ada + (long)b * E3;   // lw = 0
    float r0 = (ap[tid] + 1.f) * ((a0 - mu) * inv) + ap[512 + tid];
    float r1 = (ap[tid + 256] + 1.f) * ((a1 - mu) * inv) + ap[512 + tid + 256];
    ln16[(long)row * EDIM + tid] = f2b(r0);
    ln16[(long)row * EDIM + tid + 256] = f2b(r1);
}

// ---------------- adaLN precompute ----------------
__global__ __launch_bounds__(256) void k_adaln(const float* __restrict__ t,
    const float* __restrict__ a1W1, const float* __restrict__ a1b1, const float* __restrict__ a1W2, const float* __restrict__ a1b2,
    const float* __restrict__ a2W1, const float* __restrict__ a2b1, const float* __restrict__ a2W2, const float* __restrict__ a2b2,
    float* __restrict__ ada) {
    int blk = blockIdx.x; int b = blk & 1, lw = blk >> 1; int which = lw & 1, l = lw >> 1;
    const float* W1 = (which ? a2W1 : a1W1) + (long)l * 256 * 256;
    const float* b1 = (which ? a2b1 : a1b1) + l * 256;
    const float* W2 = (which ? a2W2 : a1W2) + (long)l * 256 * E3;
    const float* b2 = (which ? a2b2 : a1b2) + l * E3;
    __shared__ float st[256], sh[256];
    int tid = threadIdx.x;
    st[tid] = t[b * 256 + tid];
    __syncthreads();
    float a = b1[tid];
    for (int i = 0; i < 256; ++i) a += st[i] * W1[i * 256 + tid];
    sh[tid] = a / (1.f + __expf(-a));
    __syncthreads();
    int c = blockIdx.y * 256 + tid;
    float m = b2[c];
    for (int i = 0; i < 256; ++i) m += sh[i] * W2[i * E3 + c];
    ada[(long)(lw * 2 + b) * E3 + c] = m;
}

// ---------------- all weight transposes in one dispatch ----------------
__global__ __launch_bounds__(256) void k_wTall(
        const float* __restrict__ qkvW, const float* __restrict__ outW,
        const float* __restrict__ m1W, const float* __restrict__ m2W,
        ushort_t* __restrict__ qkvWt, ushort_t* __restrict__ outWt,
        ushort_t* __restrict__ m1Wt, ushort_t* __restrict__ m2Wt) {
    int idx = blockIdx.x, l = blockIdx.y;
    const float* W; ushort_t* Wt; int Kd, Nd, ntile, ktile;
    if (idx < 192)      { W = qkvW; Wt = qkvWt; Kd = 512;  Nd = 1536; ntile = idx % 24; ktile = idx / 24; }
    else if (idx < 256) { W = outW; Wt = outWt; Kd = 512;  Nd = 512;  idx -= 192; ntile = idx % 8;  ktile = idx / 8; }
    else if (idx < 512) { W = m1W;  Wt = m1Wt;  Kd = 512;  Nd = 2048; idx -= 256; ntile = idx % 32; ktile = idx / 32; }
    else                { W = m2W;  Wt = m2Wt;  Kd = 2048; Nd = 512;  idx -= 512; ntile = idx % 8;  ktile = idx / 8; }
    const float* Wp = W + (long)l * Kd * Nd;
    ushort_t* Wtp = Wt + (long)l * Kd * Nd;
    int n0 = ntile * 64, k0 = ktile * 64;
    __shared__ float s[64][65];
    int tid = threadIdx.x;
    #pragma unroll
    for (int it = 0; it < 4; ++it) {
        int i2 = tid + it * 256;
        int r = i2 >> 4, c4 = (i2 & 15) * 4;
        float4 vv = *(const float4*)(Wp + (long)(k0 + r) * Nd + n0 + c4);
        s[r][c4] = vv.x; s[r][c4 + 1] = vv.y; s[r][c4 + 2] = vv.z; s[r][c4 + 3] = vv.w;
    }
    __syncthreads();
    #pragma unroll
    for (int it = 0; it < 4; ++it) {
        int i2 = tid + it * 256;
        int rn = i2 >> 4, ck = (i2 & 15) * 4;
        long base = (long)(n0 + rn) * Kd + k0 + ck;
        #pragma unroll
        for (int j = 0; j < 4; ++j) Wtp[base + j] = f2b(s[ck + j][rn]);
    }
}

// ---------------- fused flash attention, dbuf, setprio, XCD-grouped blocks ----------------
// 1-D grid of 192; bh = (bid&7) + 8*((bid>>3)/12) so all 12 q-tiles of one
// (b,h) share an XCD slot -> K/V slices stay L2-resident.
__global__ __launch_bounds__(256) void k_attn(const ushort_t* __restrict__ qkv16,
        const ushort_t* __restrict__ vT, const ushort_t* __restrict__ biasT,
        ushort_t* __restrict__ attnb) {
    int bid = blockIdx.x;
    int xs = bid & 7, idx = bid >> 3;           // idx 0..23
    int bh = xs + 8 * (idx / 12);
    int qt = idx % 12;
    int b = bh >> 3, h = bh & 7;
    __shared__ __align__(16) ushort_t Ks[2][4096];
    __shared__ __align__(16) ushort_t Vs[2][4096];
    __shared__ __align__(16) ushort_t Bi[2][4096];
    int tid = threadIdx.x, lane = tid & 63, wave = tid >> 6;
    int g = lane >> 4, c = lane & 15;
    int ls = lane & 7, lr = lane >> 3;
    int stg_col = (ls ^ lr) * 8;
    int q0 = qt * 64;

    bf16x8 aq[2];
    {
        const ushort_t* qp = qkv16 + ((long)(b * NT + q0 + wave * 16 + c) * E3) + h * 192;
        aq[0] = *(const bf16x8*)(qp + g * 8);
        aq[1] = *(const bf16x8*)(qp + 32 + g * 8);
    }
    float m_r[4], l_r[4];
    f32x4 o_acc[4];
    #pragma unroll
    for (int rr = 0; rr < 4; ++rr) { m_r[rr] = -1e30f; l_r[rr] = 0.f; }
    #pragma unroll
    for (int nf = 0; nf < 4; ++nf) o_acc[nf] = f32x4{0.f, 0.f, 0.f, 0.f};

#define STAGEA(buf, kt) { \
        int k0_ = (kt) * 64; \
        _Pragma("unroll") \
        for (int is = 0; is < 2; ++is) { \
            int row = is * 32 + wave * 8 + lr; \
            int dstb = (is * 32 + wave * 8) * 64; \
            GLOAD(qkv16 + (long)(b * NT + k0_ + row) * E3 + h * 192 + 64 + stg_col, &Ks[buf][dstb]); \
            GLOAD(vT + ((long)bh * 64 + row) * NT + k0_ + stg_col, &Vs[buf][dstb]); \
            GLOAD(biasT + (long)bh * NT * NT + (long)(q0 + row) * NT + k0_ + ls * 8, &Bi[buf][dstb]); \
        } }

    STAGEA(0, 0);
    __syncthreads();
    int cur = 0;
    for (int kt = 0; kt < 12; ++kt) {
        if (kt + 1 < 12) STAGEA(cur ^ 1, kt + 1);
        f32x4 s[4];
        __builtin_amdgcn_s_setprio(1);
        #pragma unroll
        for (int nf = 0; nf < 4; ++nf) {
            s[nf] = f32x4{0.f, 0.f, 0.f, 0.f};
            #pragma unroll
            for (int kh = 0; kh < 2; ++kh) {
                int row = nf * 16 + c;
                bf16x8 bk = *(const bf16x8*)(&Ks[cur][row * 64 + (((kh * 4 + g) ^ (row & 7))) * 8]);
                s[nf] = __builtin_amdgcn_mfma_f32_16x16x32_bf16(aq[kh], bk, s[nf], 0, 0, 0);
            }
        }
        __builtin_amdgcn_s_setprio(0);
        float p[4][4], mt[4];
        #pragma unroll
        for (int rr = 0; rr < 4; ++rr) {
            int ql = wave * 16 + g * 4 + rr;
            #pragma unroll
            for (int nf = 0; nf < 4; ++nf)
                p[nf][rr] = s[nf][rr] * 0.125f + b2f(Bi[cur][ql * 64 + nf * 16 + c]);
            float mx = fmaxf(fmaxf(p[0][rr], p[1][rr]), fmaxf(p[2][rr], p[3][rr]));
            mx = fmaxf(mx, __shfl_xor(mx, 1));
            mx = fmaxf(mx, __shfl_xor(mx, 2));
            mx = fmaxf(mx, __shfl_xor(mx, 4));
            mx = fmaxf(mx, __shfl_xor(mx, 8));
            mt[rr] = mx;
        }
        #pragma unroll
        for (int rr = 0; rr < 4; ++rr) {
            float mnew = fmaxf(m_r[rr], mt[rr]);
            float sc = __expf(m_r[rr] - mnew);
            m_r[rr] = mnew;
            float rsum = 0.f;
            #pragma unroll
            for (int nf = 0; nf < 4; ++nf) {
                p[nf][rr] = __expf(p[nf][rr] - mnew);
                rsum += p[nf][rr];
            }
            rsum += __shfl_xor(rsum, 1); rsum += __shfl_xor(rsum, 2);
            rsum += __shfl_xor(rsum, 4); rsum += __shfl_xor(rsum, 8);
            l_r[rr] = l_r[rr] * sc + rsum;
            #pragma unroll
            for (int nf = 0; nf < 4; ++nf) o_acc[nf][rr] *= sc;
        }
        #pragma unroll
        for (int nf = 0; nf < 4; ++nf) {
            int kl = nf * 16 + c;
            int slot = kl >> 3, win = kl & 7;
            #pragma unroll
            for (int rr = 0; rr < 4; ++rr) {
                int ql = wave * 16 + g * 4 + rr;
                Bi[cur][ql * 64 + ((slot ^ (ql & 7)) * 8) + win] = f2b(p[nf][rr]);
            }
        }
        asm volatile("s_waitcnt lgkmcnt(0)" ::: "memory");
        bf16x8 ap[2];
        #pragma unroll
        for (int kh = 0; kh < 2; ++kh) {
            int ql = wave * 16 + c;
            ap[kh] = *(const bf16x8*)(&Bi[cur][ql * 64 + (((kh * 4 + g) ^ (ql & 7))) * 8]);
        }
        __builtin_amdgcn_s_setprio(1);
        #pragma unroll
        for (int nf = 0; nf < 4; ++nf) {
            #pragma unroll
            for (int kh = 0; kh < 2; ++kh) {
                int row = nf * 16 + c;
                bf16x8 bv = *(const bf16x8*)(&Vs[cur][row * 64 + (((kh * 4 + g) ^ (row & 7))) * 8]);
                o_acc[nf] = __builtin_amdgcn_mfma_f32_16x16x32_bf16(ap[kh], bv, o_acc[nf], 0, 0, 0);
            }
        }
        __builtin_amdgcn_s_setprio(0);
        __syncthreads();
        cur ^= 1;
    }
#undef STAGEA
    #pragma unroll
    for (int nf = 0; nf < 4; ++nf) {
        #pragma unroll
        for (int rr = 0; rr < 4; ++rr) {
            int ql = wave * 16 + g * 4 + rr;
            Ks[0][ql * 64 + nf * 16 + c] = f2b(o_acc[nf][rr] / l_r[rr]);
        }
    }
    asm volatile("s_waitcnt lgkmcnt(0)" ::: "memory");
    __syncthreads();
    int orow = wave * 16 + (lane >> 2);
    int ocol = (lane & 3) * 16;
    const ushort_t* srcO = &Ks[0][orow * 64 + ocol];
    ushort_t* dstO = attnb + (long)(b * NT + q0 + orow) * EDIM + h * 64 + ocol;
    *(bf16x8*)(dstO) = *(const bf16x8*)(srcO);
    *(bf16x8*)(dstO + 8) = *(const bf16x8*)(srcO + 8);
}

// ---------------- MFMA GEMM, 64x64 tile, double-buffered, K-step 64 ----------------
// EPI 0: bf16 +bias (V-cols mirrored to vTout if non-null); EPI 1: bf16 gelu(+bias);
// EPI 4: fp32 raw partial, blockIdx.z = K-chunk.
template<int EPI>
__global__ __launch_bounds__(256) void k_mm64(
        const ushort_t* __restrict__ A0, const ushort_t* __restrict__ B0,
        const float* __restrict__ bias, void* __restrict__ C0,
        int Kchunk, int lda, int ldb, int ldc, ushort_t* __restrict__ vTout) {
    __shared__ __align__(16) ushort_t As[2][4096];
    __shared__ __align__(16) ushort_t Bs[2][4096];
    int tid = threadIdx.x, lane = tid & 63, wave = tid >> 6;
    int wm = wave >> 1, wn = wave & 1;
    int m0 = blockIdx.y * 64, n0 = blockIdx.x * 64;
    int lr = lane >> 3, ls = lane & 7;
    int stg_col = (ls ^ lr) * 8;
    int r = lane & 15, g = lane >> 4, rs = r & 7;
    int nt = Kchunk >> 6;
    const ushort_t* A = A0 + (long)blockIdx.z * Kchunk;
    const ushort_t* B = B0 + (long)blockIdx.z * Kchunk;

    f32x4 acc[2][2];
    #pragma unroll
    for (int i = 0; i < 2; ++i)
        #pragma unroll
        for (int j = 0; j < 2; ++j) acc[i][j] = f32x4{0.f, 0.f, 0.f, 0.f};

#define STAGE64(buf, t) { \
        int k0_ = (t) * 64; \
        _Pragma("unroll") \
        for (int c0 = 0; c0 < 4; ++c0) { \
            int ch = wave * 4 + c0; \
            if (ch < 8) { \
                GLOAD(A + (long)(m0 + ch * 8 + lr) * lda + k0_ + stg_col, &As[buf][ch * 512]); \
            } else { \
                GLOAD(B + (long)(n0 + (ch - 8) * 8 + lr) * ldb + k0_ + stg_col, &Bs[buf][(ch - 8) * 512]); \
            } \
        } }

    STAGE64(0, 0);
    __syncthreads();
    int cur = 0;
    for (int t = 0; t < nt; ++t) {
        if (t + 1 < nt) STAGE64(cur ^ 1, t + 1);
        bf16x8 af[2][2], bfr[2][2];
        #pragma unroll
        for (int i = 0; i < 2; ++i) {
            int row = wm * 32 + i * 16 + r;
            #pragma unroll
            for (int kh = 0; kh < 2; ++kh)
                af[i][kh] = *(const bf16x8*)(&As[cur][row * 64 + (((kh * 4 + g) ^ rs)) * 8]);
        }
        #pragma unroll
        for (int j = 0; j < 2; ++j) {
            int row = wn * 32 + j * 16 + r;
            #pragma unroll
            for (int kh = 0; kh < 2; ++kh)
                bfr[j][kh] = *(const bf16x8*)(&Bs[cur][row * 64 + (((kh * 4 + g) ^ rs)) * 8]);
        }
        #pragma unroll
        for (int kh = 0; kh < 2; ++kh)
            #pragma unroll
            for (int i = 0; i < 2; ++i)
                #pragma unroll
                for (int j = 0; j < 2; ++j)
                    acc[i][j] = __builtin_amdgcn_mfma_f32_16x16x32_bf16(af[i][kh], bfr[j][kh], acc[i][j], 0, 0, 0);
        __syncthreads();
        cur ^= 1;
    }
#undef STAGE64

    int gr4 = g * 4, cL = lane & 15;
    if constexpr (EPI == 0 || EPI == 1) {
        ushort_t* C = (ushort_t*)C0;
        #pragma unroll
        for (int i = 0; i < 2; ++i) {
            int mrow = m0 + wm * 32 + i * 16 + gr4;
            #pragma unroll
            for (int j = 0; j < 2; ++j) {
                int n = n0 + wn * 32 + j * 16 + cL;
                float bn = bias[n];
                ushort_t o[4];
                #pragma unroll
                for (int rr = 0; rr < 4; ++rr) {
                    float vv = acc[i][j][rr] + bn;
                    if constexpr (EPI == 1) vv = gelu_tanh(vv);
                    o[rr] = f2b(vv);
                    C[(long)(mrow + rr) * ldc + n] = o[rr];
                }
                if constexpr (EPI == 0) {
                    if (vTout) {
                        int seg = n % 192;
                        if (seg >= 128) {
                            int h = n / 192, d = seg - 128;
                            int b2 = (mrow >= NT) ? 1 : 0;
                            int tok = mrow - b2 * NT;
                            uint2 pk;
                            pk.x = (unsigned int)o[0] | ((unsigned int)o[1] << 16);
                            pk.y = (unsigned int)o[2] | ((unsigned int)o[3] << 16);
                            *(uint2*)(vTout + ((long)((b2 * 8 + h) * 64 + d)) * NT + tok) = pk;
                        }
                    }
                }
            }
        }
    } else {
        float* C = (float*)C0 + (long)blockIdx.z * (1536 * 512);
        #pragma unroll
        for (int i = 0; i < 2; ++i) {
            int mrow = m0 + wm * 32 + i * 16 + gr4;
            #pragma unroll
            for (int j = 0; j < 2; ++j) {
                int n = n0 + wn * 32 + j * 16 + cL;
                #pragma unroll
                for (int rr = 0; rr < 4; ++rr)
                    C[(long)(mrow + rr) * ldc + n] = acc[i][j][rr];
            }
        }
    }
}

// ---------------- split-K reduce + bias + scaled residual + next LN/modulate ----------------
__global__ __launch_bounds__(256) void k_redln(const float* __restrict__ P, int kSplit,
        const float* __restrict__ bias, const float* __restrict__ ada,
        int lw_res, int lw_next,
        const float* __restrict__ xin, float* __restrict__ xout,
        ushort_t* __restrict__ lnout) {
    int tid = threadIdx.x;
    int row = blockIdx.x * 2 + (tid >> 7);
    int col = (tid & 127) * 4;
    int b = (row >= NT) ? 1 : 0;
    long idx = (long)row * EDIM + col;
    float4 s = *(const float4*)(P + idx);
    for (int kc = 1; kc < kSplit; ++kc) {
        float4 p = *(const float4*)(P + (long)kc * (1536 * 512) + idx);
        s.x += p.x; s.y += p.y; s.z += p.z; s.w += p.w;
    }
    float4 bv = *(const float4*)(bias + col);
    const float* al = ada + (long)(lw_res * 2 + b) * E3 + 1024;
    float4 av = *(const float4*)(al + col);
    float4 xv = *(const float4*)(xin + idx);
    float4 r;
    r.x = xv.x + av.x * rsqrtf(1.f + av.x * av.x) * (s.x + bv.x);
    r.y = xv.y + av.y * rsqrtf(1.f + av.y * av.y) * (s.y + bv.y);
    r.z = xv.z + av.z * rsqrtf(1.f + av.z * av.z) * (s.z + bv.z);
    r.w = xv.w + av.w * rsqrtf(1.f + av.w * av.w) * (s.w + bv.w);
    *(float4*)(xout + idx) = r;

    if (lnout) {
        float s1 = r.x + r.y + r.z + r.w;
        float s2 = r.x * r.x + r.y * r.y + r.z * r.z + r.w * r.w;
        for (int o = 32; o; o >>= 1) { s1 += __shfl_xor(s1, o); s2 += __shfl_xor(s2, o); }
        __shared__ float sm[8];
        int w = tid >> 6;
        if ((tid & 63) == 0) { sm[w] = s1; sm[4 + w] = s2; }
        __syncthreads();
        int p2 = (tid >> 7) * 2;
        s1 = sm[p2] + sm[p2 + 1];
        s2 = sm[4 + p2] + sm[4 + p2 + 1];
        float mu = s1 * (1.f / 512.f);
        float var = s2 * (1.f / 512.f) - mu * mu;
        float inv = rsqrtf(var + 1e-6f);
        const float* ap = ada + (long)(lw_next * 2 + b) * E3;
        float4 gv = *(const float4*)(ap + col);
        float4 bev = *(const float4*)(ap + 512 + col);
        ushort_t o4[4];
        o4[0] = f2b((gv.x + 1.f) * ((r.x - mu) * inv) + bev.x);
        o4[1] = f2b((gv.y + 1.f) * ((r.y - mu) * inv) + bev.y);
        o4[2] = f2b((gv.z + 1.f) * ((r.z - mu) * inv) + bev.z);
        o4[3] = f2b((gv.w + 1.f) * ((r.w - mu) * inv) + bev.w);
        uint2 pk;
        pk.x = (unsigned int)o4[0] | ((unsigned int)o4[1] << 16);
        pk.y = (unsigned int)o4[2] | ((unsigned int)o4[3] << 16);
        *(uint2*)(lnout + idx) = pk;
    }
}

extern "C" void kernel_launch(void* const* d_in, const int* in_sizes, int n_in,
                              void* d_out, int out_size, void* d_ws, size_t ws_size,
                              hipStream_t stream) {
    const float* x       = (const float*)d_in[0];
    const float* t       = (const float*)d_in[1];
    const float* vec_map = (const float*)d_in[2];
    const float* W_rb    = (const float*)d_in[3];
    const float* b_rb    = (const float*)d_in[4];
    const float* W_embed = (const float*)d_in[5];
    const float* b_embed = (const float*)d_in[6];
    const float* pos_emb = (const float*)d_in[7];
    const float* a1W1    = (const float*)d_in[8];
    const float* a1b1    = (const float*)d_in[9];
    const float* a1W2    = (const float*)d_in[10];
    const float* a1b2    = (const float*)d_in[11];
    const float* qkv_W   = (const float*)d_in[12];
    const float* qkv_b   = (const float*)d_in[13];
    const float* out_W   = (const float*)d_in[14];
    const float* out_b   = (const float*)d_in[15];
    const float* a2W1    = (const float*)d_in[16];
    const float* a2b1    = (const float*)d_in[17];
    const float* a2W2    = (const float*)d_in[18];
    const float* a2b2    = (const float*)d_in[19];
    const float* mlp_W1  = (const float*)d_in[20];
    const float* mlp_b1  = (const float*)d_in[21];
    const float* mlp_W2  = (const float*)d_in[22];
    const float* mlp_b2  = (const float*)d_in[23];

    float* ws = (float*)d_ws;
    size_t o = 0;
    ushort_t* biasT = (ushort_t*)(ws + o); o += 4718592;   // 16*768*768 bf16
    float* ada      = ws + o; o += 24576;
    float* xc       = ws + o; o += 786432;
    ushort_t* ln16  = (ushort_t*)(ws + o); o += 393216;    // 1536x512
    ushort_t* qkv16 = (ushort_t*)(ws + o); o += 1179648;   // 1536x1536
    ushort_t* vT    = (ushort_t*)(ws + o); o += 393216;    // 16x64x768
    ushort_t* attnb = (ushort_t*)(ws + o); o += 393216;    // 1536x512
    ushort_t* mlph  = (ushort_t*)(ws + o); o += 1572864;   // 1536x2048
    ushort_t* qkvWt = (ushort_t*)(ws + o); o += 1572864;   // 4x1536x512
    ushort_t* outWt = (ushort_t*)(ws + o); o += 524288;    // 4x512x512
    ushort_t* mlp1Wt = (ushort_t*)(ws + o); o += 2097152;  // 4x2048x512
    ushort_t* mlp2Wt = (ushort_t*)(ws + o); o += 2097152;  // 4x512x2048
    float* P        = ws + o; o += 3145728;                // 4 x 1536x512 f32

    k_adaln<<<dim3(16, 6), 256, 0, stream>>>(t, a1W1, a1b1, a1W2, a1b2, a2W1, a2b1, a2W2, a2b2, ada);
    k_bias<<<TB * NT, 256, 0, stream>>>(vec_map, W_rb, b_rb, biasT);
    k_embedln<<<TB * NT, 256, 0, stream>>>(x, W_embed, b_embed, pos_emb, ada, xc, ln16);
    k_wTall<<<dim3(768, 4), 256, 0, stream>>>(qkv_W, out_W, mlp_W1, mlp_W2,
                                              qkvWt, outWt, mlp1Wt, mlp2Wt);

    for (int l = 0; l < 4; ++l) {
        int lw0 = l * 2, lw1 = l * 2 + 1;
        // --- attention half (ln16 holds modulated LN for lw0) ---
        k_mm64<0><<<dim3(24, 24, 1), 256, 0, stream>>>(
            ln16, qkvWt + (long)l * 786432, qkv_b + l * E3,
            qkv16, 512, 512, 512, E3, vT);
        k_attn<<<192, 256, 0, stream>>>(qkv16, vT, biasT, attnb);
        k_mm64<4><<<dim3(8, 24, 2), 256, 0, stream>>>(
            attnb, outWt + (long)l * 262144, nullptr,
            P, 256, 512, 512, EDIM, nullptr);
        k_redln<<<768, 256, 0, stream>>>(P, 2, out_b + l * EDIM, ada, lw0, lw1, xc, xc, ln16);
        // --- mlp half (ln16 now holds lw1) ---
        k_mm64<1><<<dim3(32, 24, 1), 256, 0, stream>>>(
            ln16, mlp1Wt + (long)l * 1048576, mlp_b1 + l * E4,
            mlph, 512, 512, 512, E4, nullptr);
        k_mm64<4><<<dim3(8, 24, 4), 256, 0, stream>>>(
            mlph, mlp2Wt + (long)l * 1048576, nullptr,
            P, 512, 2048, 2048, EDIM, nullptr);
        k_redln<<<768, 256, 0, stream>>>(P, 4, mlp_b2 + l * EDIM, ada, lw1, lw1 + 1,
            xc, (l == 3) ? (float*)d_out : xc, (l == 3) ? nullptr : ln16);
    }
}